// Round 2
// baseline (472.168 us; speedup 1.0000x reference)
//
#include <hip/hip_runtime.h>
#include <math.h>

#define NB 32
#define NS 384
#define NLM 543
#define NL 67
#define NF 743
#define NCH 48            // 8-row chunks per batch element
#define ENTRY 72          // floats per (b,chunk) workspace entry (288 B)
#define FLAG_OFF 68       // float index of the 8-byte flag (byte 272, 8-aligned)
#define MAGIC 0xF00DFACE5EEDC0DEull   // two DISTINCT dwords: a repeated-pattern
                                      // poison fill can never equal this

// SEL = FACE(19) + [468..488](21) + [522..542](21) + [11..16](6) = 67
__constant__ int d_SEL[NL] = {
    33, 133, 362, 263, 61, 291, 199, 419, 17, 84, 314, 405, 320, 307, 375, 321, 308, 324, 318,
    468, 469, 470, 471, 472, 473, 474, 475, 476, 477, 478, 479, 480, 481, 482, 483, 484, 485, 486, 487, 488,
    522, 523, 524, 525, 526, 527, 528, 529, 530, 531, 532, 533, 534, 535, 536, 537, 538, 539, 540, 541, 542,
    11, 12, 13, 14, 15, 16
};

__device__ __forceinline__ float fin(float v) { return isfinite(v) ? v : 0.0f; }

// Feature layout per (b,s) row of 743 floats:
// c:[0,134) vel:[134,268) acc:[268,402) vm:[402,469) am:[469,536)
// cum:[536,603) ang:[603,670) dchg:[670,737) dists:[737,743)

__device__ __forceinline__ void gather_norm(const float* __restrict__ xr,
                                            int o0, int o1, bool has1,
                                            float& c0x, float& c0y,
                                            float& c1x, float& c1y) {
    float a0x = xr[o0], a0y = xr[o0 + 1];
    float a1x = 0.f, a1y = 0.f;
    if (has1) { a1x = xr[o1]; a1y = xr[o1 + 1]; }

    float sx = a0x + a1x, sy = a0y + a1y;
    #pragma unroll
    for (int off = 32; off; off >>= 1) { sx += __shfl_xor(sx, off); sy += __shfl_xor(sy, off); }
    const float mx = sx * (1.0f / 67.0f), my = sy * (1.0f / 67.0f);

    c0x = a0x - mx; c0y = a0y - my;
    c1x = a1x - mx; c1y = a1y - my;

    float ss = c0x * c0x + c0y * c0y + (has1 ? (c1x * c1x + c1y * c1y) : 0.f);
    #pragma unroll
    for (int off = 32; off; off >>= 1) ss += __shfl_xor(ss, off);
    const float stdv = sqrtf(ss * (1.0f / 133.0f));
    const float scale = (stdv > 1e-6f) ? (1.0f / stdv) : 1.0f;

    c0x *= scale; c0y *= scale; c1x *= scale; c1y *= scale;
}

// Single fused kernel. Block = 8 consecutive s of one b (8 waves, 512 threads).
// Phases:
//   A) gather+normalize (own row + 2 boundary rows) -> csh
//   B) vel+vm only -> vm_sh; wave 0 publishes the 67 chunk aggregates to ws
//      with a release-flag (decoupled-lookback publish, done EARLY so
//      successors' polls hit ready flags)
//   C) the expensive phase: acc/am/ang/dists + 9 out-stores per lm (hides
//      predecessors' publish latency)
//   D) aggregate-only lookback: wave w polls chunks w, w+8, ... (acquire +
//      s_sleep spin; never waits on a successor -> deadlock-free), LDS
//      reduce, write cum directly. k_scan and vmstage are gone.
__global__ __launch_bounds__(512) void k_main(const float* __restrict__ x,
                                              float* __restrict__ out,
                                              float* __restrict__ part) {
    __shared__ float2 csh[10][NL];   // c rows s_base-2 .. s_base+7
    __shared__ float ang_sh[9][NL];  // ang rows s_base-1 .. s_base+7
    __shared__ float vm_sh[8][NL];   // vm rows s_base .. s_base+7
    __shared__ float pref_sh[8][NL]; // per-wave lookback partials

    const int wave = threadIdx.x >> 6;
    const int lane = threadIdx.x & 63;
    const int b = blockIdx.x / NCH;
    const int chunk = blockIdx.x - b * NCH;
    const int s_base = chunk * 8;
    const int s = s_base + wave;
    const int bs = b * NS + s;

    const int lm0 = lane;
    const bool has1 = (lane < 3);
    const int lm1 = lane + 64;
    const int o0 = d_SEL[lm0] * 3;
    const int o1 = has1 ? d_SEL[lm1] * 3 : 0;

    const float* __restrict__ xb = x + (size_t)(b * NS) * (NLM * 3);

    // ---- Phase A: gathers ----
    float c0x, c0y, c1x, c1y;
    gather_norm(xb + (size_t)s * (NLM * 3), o0, o1, has1, c0x, c0y, c1x, c1y);
    csh[wave + 2][lm0] = make_float2(c0x, c0y);
    if (has1) csh[wave + 2][lm1] = make_float2(c1x, c1y);

    if (wave == 0) {
        if (s_base >= 1) {
            float bx, by, b1x, b1y;
            gather_norm(xb + (size_t)(s_base - 1) * (NLM * 3), o0, o1, has1, bx, by, b1x, b1y);
            csh[1][lm0] = make_float2(bx, by);
            if (has1) csh[1][lm1] = make_float2(b1x, b1y);
        } else {
            csh[1][lm0] = make_float2(0.f, 0.f);
            if (has1) csh[1][lm1] = make_float2(0.f, 0.f);
        }
    }
    if (wave == 1) {
        if (s_base >= 2) {
            float bx, by, b1x, b1y;
            gather_norm(xb + (size_t)(s_base - 2) * (NLM * 3), o0, o1, has1, bx, by, b1x, b1y);
            csh[0][lm0] = make_float2(bx, by);
            if (has1) csh[0][lm1] = make_float2(b1x, b1y);
        } else {
            csh[0][lm0] = make_float2(0.f, 0.f);
            if (has1) csh[0][lm1] = make_float2(0.f, 0.f);
        }
    }
    __syncthreads();   // S1: csh ready

    // ---- Phase B: vel + vm only; publish aggregates ASAP ----
    float vx0, vy0, vmv0, vx1 = 0.f, vy1 = 0.f, vmv1 = 0.f;
    {
        const float2 p = csh[wave + 1][lm0];
        vx0 = (s >= 1) ? (c0x - p.x) : 0.f;
        vy0 = (s >= 1) ? (c0y - p.y) : 0.f;
        const float wx = vx0 + 1e-8f, wy = vy0 + 1e-8f;
        vmv0 = sqrtf(wx * wx + wy * wy);
        vm_sh[wave][lm0] = vmv0;
    }
    if (has1) {
        const float2 p = csh[wave + 1][lm1];
        vx1 = (s >= 1) ? (c1x - p.x) : 0.f;
        vy1 = (s >= 1) ? (c1y - p.y) : 0.f;
        const float wx = vx1 + 1e-8f, wy = vy1 + 1e-8f;
        vmv1 = sqrtf(wx * wx + wy * wy);
        vm_sh[wave][lm1] = vmv1;
    }
    __syncthreads();   // S2: vm_sh ready

    float* entry = part + (size_t)blockIdx.x * ENTRY;
    if (wave == 0) {
        float a0 = 0.f;
        #pragma unroll
        for (int r = 0; r < 8; ++r) a0 += vm_sh[r][lm0];
        __hip_atomic_store(&entry[lm0], a0, __ATOMIC_RELAXED, __HIP_MEMORY_SCOPE_AGENT);
        if (has1) {
            float a1 = 0.f;
            #pragma unroll
            for (int r = 0; r < 8; ++r) a1 += vm_sh[r][lm1];
            __hip_atomic_store(&entry[lm1], a1, __ATOMIC_RELAXED, __HIP_MEMORY_SCOPE_AGENT);
        }
        // Release store: compiler emits the per-wave vmcnt drain + agent-scope
        // cache ops, ordering ALL of this wave's agg stores before the flag.
        if (lane == 0) {
            __hip_atomic_store((unsigned long long*)(entry + FLAG_OFF), MAGIC,
                               __ATOMIC_RELEASE, __HIP_MEMORY_SCOPE_AGENT);
        }
    }

    // ---- Phase C: remaining features + out stores (hides publish latency) ----
    float* __restrict__ row = out + (size_t)bs * NF;
    float ang0_own = 0.f, ang1_own = 0.f;

    #pragma unroll
    for (int half = 0; half < 2; ++half) {
        if (half == 1 && !has1) break;
        const int lm = half ? lm1 : lm0;
        const float cx = half ? c1x : c0x, cy = half ? c1y : c0y;
        const float vx = half ? vx1 : vx0, vy = half ? vy1 : vy0;
        const float vmv = half ? vmv1 : vmv0;
        const float2 p = csh[wave + 1][lm];
        const float2 q = csh[wave][lm];

        const float v1x = p.x - q.x, v1y = p.y - q.y;   // vel[s-1], valid when s>=2
        const float ax = (s >= 2) ? (vx - v1x) : 0.f;
        const float ay = (s >= 2) ? (vy - v1y) : 0.f;

        const float ux = ax + 1e-8f, uy = ay + 1e-8f;
        const float am = sqrtf(ux * ux + uy * uy);

        const float ang = atan2f(vy + 1e-8f, vx + 1e-8f);
        if (half) ang1_own = ang; else ang0_own = ang;
        ang_sh[wave + 1][lm] = ang;

        row[2 * lm]       = fin(cx);
        row[2 * lm + 1]   = fin(cy);
        row[134 + 2 * lm] = vx;
        row[135 + 2 * lm] = vy;
        row[268 + 2 * lm] = ax;
        row[269 + 2 * lm] = ay;
        row[402 + lm]     = vmv;
        row[469 + lm]     = am;
        row[603 + lm]     = fin(ang);
    }

    // wave 0: angle of boundary row s_base-1 from vel = csh[1]-csh[0].
    // Slots zeroed when out of range; result then unused (dchg needs s>=2).
    if (wave == 0) {
        float bvx = csh[1][lm0].x - csh[0][lm0].x;
        float bvy = csh[1][lm0].y - csh[0][lm0].y;
        ang_sh[0][lm0] = atan2f(bvy + 1e-8f, bvx + 1e-8f);
        if (has1) {
            bvx = csh[1][lm1].x - csh[0][lm1].x;
            bvy = csh[1][lm1].y - csh[0][lm1].y;
            ang_sh[0][lm1] = atan2f(bvy + 1e-8f, bvx + 1e-8f);
        }
    }

    // 6 pairwise dists among selected landmarks 0..4 (held in lanes 0..4)
    const int PI_[6] = {0, 0, 1, 1, 2, 2};
    const int PJ_[6] = {1, 2, 2, 3, 3, 4};
    const int pp = (lane < 6) ? lane : 0;
    float xi = __shfl(c0x, PI_[pp]); float yi = __shfl(c0y, PI_[pp]);
    float xj = __shfl(c0x, PJ_[pp]); float yj = __shfl(c0y, PJ_[pp]);
    if (lane < 6) {
        float dx = xi - xj + 1e-8f, dy = yi - yj + 1e-8f;
        row[737 + lane] = fin(sqrtf(dx * dx + dy * dy));
    }

    __syncthreads();   // S3: ang_sh ready

    // dchg = ang[s] - ang[s-1]; prev-row angle from LDS
    if (s >= 2) {
        row[670 + lm0] = fin(ang0_own - ang_sh[wave][lm0]);
        if (has1) row[670 + lm1] = fin(ang1_own - ang_sh[wave][lm1]);
    } else {
        row[670 + lm0] = 0.f;
        if (has1) row[670 + lm1] = 0.f;
    }

    // ---- Phase D: aggregate-only lookback + cum write ----
    float lb0 = 0.f, lb1 = 0.f;
    for (int pc = wave; pc < chunk; pc += 8) {
        float* e = part + (size_t)(b * NCH + pc) * ENTRY;
        while (__hip_atomic_load((unsigned long long*)(e + FLAG_OFF),
                                 __ATOMIC_ACQUIRE, __HIP_MEMORY_SCOPE_AGENT) != MAGIC) {
            __builtin_amdgcn_s_sleep(2);
        }
        lb0 += __hip_atomic_load(&e[lm0], __ATOMIC_RELAXED, __HIP_MEMORY_SCOPE_AGENT);
        if (has1) lb1 += __hip_atomic_load(&e[lm1], __ATOMIC_RELAXED, __HIP_MEMORY_SCOPE_AGENT);
    }
    pref_sh[wave][lm0] = lb0;
    if (has1) pref_sh[wave][lm1] = lb1;
    __syncthreads();   // S4: pref_sh ready

    {
        float cp0 = 0.f;
        #pragma unroll
        for (int w2 = 0; w2 < 8; ++w2) cp0 += pref_sh[w2][lm0];
        float loc0 = 0.f;
        for (int r = 0; r < wave; ++r) loc0 += vm_sh[r][lm0];
        row[536 + lm0] = fin(cp0 + loc0);
        if (has1) {
            float cp1 = 0.f;
            #pragma unroll
            for (int w2 = 0; w2 < 8; ++w2) cp1 += pref_sh[w2][lm1];
            float loc1 = 0.f;
            for (int r = 0; r < wave; ++r) loc1 += vm_sh[r][lm1];
            row[536 + lm1] = fin(cp1 + loc1);
        }
    }
}

extern "C" void kernel_launch(void* const* d_in, const int* in_sizes, int n_in,
                              void* d_out, int out_size, void* d_ws, size_t ws_size,
                              hipStream_t stream) {
    const float* x = (const float*)d_in[0];
    float* out = (float*)d_out;
    float* part = (float*)d_ws;   // 32*48*72*4 = 442 KB (poisoned each iter;
                                  // flags validated by 2-dword magic, no init needed)

    k_main<<<NB * NCH, 512, 0, stream>>>(x, out, part);   // 1536 blocks
}

// Round 3
// 132.240 us; speedup vs baseline: 3.5705x; 3.5705x over previous
//
#include <hip/hip_runtime.h>
#include <math.h>

#define NB 32
#define NS 384
#define NLM 543
#define NL 67
#define NF 743

// SEL = FACE(19) + [468..488](21) + [522..542](21) + [11..16](6) = 67
__constant__ int d_SEL[NL] = {
    33, 133, 362, 263, 61, 291, 199, 419, 17, 84, 314, 405, 320, 307, 375, 321, 308, 324, 318,
    468, 469, 470, 471, 472, 473, 474, 475, 476, 477, 478, 479, 480, 481, 482, 483, 484, 485, 486, 487, 488,
    522, 523, 524, 525, 526, 527, 528, 529, 530, 531, 532, 533, 534, 535, 536, 537, 538, 539, 540, 541, 542,
    11, 12, 13, 14, 15, 16
};

__device__ __forceinline__ float fin(float v) { return isfinite(v) ? v : 0.0f; }
__device__ __forceinline__ void ntst(float v, float* p) { __builtin_nontemporal_store(v, p); }

// Feature layout per (b,s) row of 743 floats:
// c:[0,134) vel:[134,268) acc:[268,402) vm:[402,469) am:[469,536)
// cum:[536,603) ang:[603,670) dchg:[670,737) dists:[737,743)

__device__ __forceinline__ void gather_norm(const float* __restrict__ xr,
                                            int o0, int o1, bool has1,
                                            float& c0x, float& c0y,
                                            float& c1x, float& c1y) {
    float a0x = xr[o0], a0y = xr[o0 + 1];
    float a1x = 0.f, a1y = 0.f;
    if (has1) { a1x = xr[o1]; a1y = xr[o1 + 1]; }

    float sx = a0x + a1x, sy = a0y + a1y;
    #pragma unroll
    for (int off = 32; off; off >>= 1) { sx += __shfl_xor(sx, off); sy += __shfl_xor(sy, off); }
    const float mx = sx * (1.0f / 67.0f), my = sy * (1.0f / 67.0f);

    c0x = a0x - mx; c0y = a0y - my;
    c1x = a1x - mx; c1y = a1y - my;

    float ss = c0x * c0x + c0y * c0y + (has1 ? (c1x * c1x + c1y * c1y) : 0.f);
    #pragma unroll
    for (int off = 32; off; off >>= 1) ss += __shfl_xor(ss, off);
    const float stdv = sqrtf(ss * (1.0f / 133.0f));
    const float scale = (stdv > 1e-6f) ? (1.0f / stdv) : 1.0f;

    c0x *= scale; c0y *= scale; c1x *= scale; c1y *= scale;
}

// K_main: block = 8 consecutive s of one b (8 waves, 512 threads). Round-1
// structure (the in-kernel lookback fusion of round 2 regressed 2.8x: cross-XCD
// flag visibility is hundreds of us on this chip — kernel-boundary sync is
// cheaper). This round: all `out` stores are non-temporal (out is write-only;
// keep L2 for the scattered x-gathers and vmstage).
__global__ __launch_bounds__(512) void k_main(const float* __restrict__ x,
                                              float* __restrict__ out,
                                              float* __restrict__ vmstage) {
    __shared__ float2 csh[10][NL];   // c rows s_base-2 .. s_base+7
    __shared__ float ang_sh[9][NL];  // ang rows s_base-1 .. s_base+7
    __shared__ float vm_sh[8][NL];   // vm rows s_base .. s_base+7

    const int wave = threadIdx.x >> 6;
    const int lane = threadIdx.x & 63;
    const int b = blockIdx.x / 48;              // 48 blocks per batch (384/8)
    const int s_base = (blockIdx.x - b * 48) * 8;
    const int s = s_base + wave;
    const int bs = b * NS + s;

    const int lm0 = lane;
    const bool has1 = (lane < 3);
    const int lm1 = lane + 64;
    const int o0 = d_SEL[lm0] * 3;
    const int o1 = has1 ? d_SEL[lm1] * 3 : 0;

    const float* __restrict__ xb = x + (size_t)(b * NS) * (NLM * 3);

    // own row -> slot wave+2
    float c0x, c0y, c1x, c1y;
    gather_norm(xb + (size_t)s * (NLM * 3), o0, o1, has1, c0x, c0y, c1x, c1y);
    csh[wave + 2][lm0] = make_float2(c0x, c0y);
    if (has1) csh[wave + 2][lm1] = make_float2(c1x, c1y);

    // boundary rows -> slots 1, 0 (zero if out of range)
    if (wave == 0) {
        if (s_base >= 1) {
            float bx, by, b1x, b1y;
            gather_norm(xb + (size_t)(s_base - 1) * (NLM * 3), o0, o1, has1, bx, by, b1x, b1y);
            csh[1][lm0] = make_float2(bx, by);
            if (has1) csh[1][lm1] = make_float2(b1x, b1y);
        } else {
            csh[1][lm0] = make_float2(0.f, 0.f);
            if (has1) csh[1][lm1] = make_float2(0.f, 0.f);
        }
    }
    if (wave == 1) {
        if (s_base >= 2) {
            float bx, by, b1x, b1y;
            gather_norm(xb + (size_t)(s_base - 2) * (NLM * 3), o0, o1, has1, bx, by, b1x, b1y);
            csh[0][lm0] = make_float2(bx, by);
            if (has1) csh[0][lm1] = make_float2(b1x, b1y);
        } else {
            csh[0][lm0] = make_float2(0.f, 0.f);
            if (has1) csh[0][lm1] = make_float2(0.f, 0.f);
        }
    }
    __syncthreads();

    float* __restrict__ row = out + (size_t)bs * NF;

    float ang0_own = 0.f, ang1_own = 0.f;

    #pragma unroll
    for (int half = 0; half < 2; ++half) {
        if (half == 1 && !has1) break;
        const int lm = half ? lm1 : lm0;
        const float cx = half ? c1x : c0x, cy = half ? c1y : c0y;
        const float2 p = csh[wave + 1][lm];     // row s-1
        const float2 q = csh[wave][lm];         // row s-2

        const float vx = (s >= 1) ? (cx - p.x) : 0.f;
        const float vy = (s >= 1) ? (cy - p.y) : 0.f;
        const float v1x = p.x - q.x, v1y = p.y - q.y;   // vel[s-1], valid when s>=2
        const float ax = (s >= 2) ? (vx - v1x) : 0.f;
        const float ay = (s >= 2) ? (vy - v1y) : 0.f;

        const float wx = vx + 1e-8f, wy = vy + 1e-8f;
        const float vm = sqrtf(wx * wx + wy * wy);
        const float ux = ax + 1e-8f, uy = ay + 1e-8f;
        const float am = sqrtf(ux * ux + uy * uy);

        const float ang = atan2f(vy + 1e-8f, vx + 1e-8f);
        if (half) ang1_own = ang; else ang0_own = ang;
        ang_sh[wave + 1][lm] = ang;
        vm_sh[wave][lm] = vm;

        ntst(fin(cx), &row[2 * lm]);
        ntst(fin(cy), &row[2 * lm + 1]);
        ntst(vx,      &row[134 + 2 * lm]);
        ntst(vy,      &row[135 + 2 * lm]);
        ntst(ax,      &row[268 + 2 * lm]);
        ntst(ay,      &row[269 + 2 * lm]);
        ntst(vm,      &row[402 + lm]);
        ntst(am,      &row[469 + lm]);
        ntst(fin(ang),&row[603 + lm]);
    }

    // wave 0: angle of boundary row s_base-1 from vel = csh[1]-csh[0].
    // Both slots are zeroed when out of range, and the result is then unused
    // (dchg needs s>=2, and s_base==0 rows 0,1 write zero).
    if (wave == 0) {
        float bvx = csh[1][lm0].x - csh[0][lm0].x;
        float bvy = csh[1][lm0].y - csh[0][lm0].y;
        ang_sh[0][lm0] = atan2f(bvy + 1e-8f, bvx + 1e-8f);
        if (has1) {
            bvx = csh[1][lm1].x - csh[0][lm1].x;
            bvy = csh[1][lm1].y - csh[0][lm1].y;
            ang_sh[0][lm1] = atan2f(bvy + 1e-8f, bvx + 1e-8f);
        }
    }

    // 6 pairwise dists among selected landmarks 0..4 (held in lanes 0..4)
    const int PI_[6] = {0, 0, 1, 1, 2, 2};
    const int PJ_[6] = {1, 2, 2, 3, 3, 4};
    const int p = (lane < 6) ? lane : 0;
    float xi = __shfl(c0x, PI_[p]); float yi = __shfl(c0y, PI_[p]);
    float xj = __shfl(c0x, PJ_[p]); float yj = __shfl(c0y, PJ_[p]);
    if (lane < 6) {
        float dx = xi - xj + 1e-8f, dy = yi - yj + 1e-8f;
        ntst(fin(sqrtf(dx * dx + dy * dy)), &row[737 + lane]);
    }

    __syncthreads();

    // dchg = ang[s] - ang[s-1]; prev-row angle from LDS (same fp value as the
    // inline recompute: identical formula on identical inputs)
    if (s >= 2) {
        ntst(fin(ang0_own - ang_sh[wave][lm0]), &row[670 + lm0]);
        if (has1) ntst(fin(ang1_own - ang_sh[wave][lm1]), &row[670 + lm1]);
    } else {
        ntst(0.f, &row[670 + lm0]);
        if (has1) ntst(0.f, &row[670 + lm1]);
    }

    // Cooperative transposed vmstage write: consecutive threads cover the 8
    // consecutive s of one lm -> 32B contiguous chunks. Cached (k_scan reads it).
    for (int t = threadIdx.x; t < NL * 8; t += 512) {
        const int lm = t >> 3, s8 = t & 7;
        vmstage[((size_t)b * NL + lm) * NS + s_base + s8] = vm_sh[s8][lm];
    }
}

// K_scan: one block per (b, landmark-group) = 32 x 9 = 288 blocks, 512 threads.
// Groups: g<4 -> 8 landmarks, g>=4 -> 7 (4*8+5*7=67). Every wave runs exactly
// <=1 scan chain (round-1's wave 0 serialized 3). Coalesced 256B reads from the
// transposed stage, identical shfl-scan fp order; coalesced nt burst writes.
__global__ __launch_bounds__(512) void k_scan(const float* __restrict__ vmstage,
                                              float* __restrict__ out) {
    __shared__ float cum_sh[NS][9];   // 13.8 KB; stride 9 -> 2-way banks (free)

    const int b = blockIdx.x / 9;
    const int g = blockIdx.x - b * 9;
    const int lm0 = (g < 4) ? g * 8 : 32 + (g - 4) * 7;
    const int cnt = (g < 4) ? 8 : 7;
    const int wave = threadIdx.x >> 6;
    const int lane = threadIdx.x & 63;

    if (wave < cnt) {
        const float* __restrict__ src = vmstage + ((size_t)b * NL + lm0 + wave) * NS;
        float carry = 0.f;
        #pragma unroll
        for (int k = 0; k < 6; ++k) {
            const float v = src[k * 64 + lane];
            float incl = v;
            #pragma unroll
            for (int off = 1; off < 64; off <<= 1) {
                float y = __shfl_up(incl, off);
                if (lane >= off) incl += y;
            }
            cum_sh[k * 64 + lane][wave] = carry + (incl - v);
            carry += __shfl(incl, 63);
        }
    }
    __syncthreads();

    const int total = NS * cnt;
    if (cnt == 8) {
        for (int idx = threadIdx.x; idx < total; idx += 512) {
            const int ss = idx >> 3;
            const int j = idx & 7;
            ntst(fin(cum_sh[ss][j]), &out[((size_t)(b * NS + ss)) * NF + 536 + lm0 + j]);
        }
    } else {
        for (int idx = threadIdx.x; idx < total; idx += 512) {
            const int ss = idx / 7;             // compiler magic-mul
            const int j = idx - ss * 7;
            ntst(fin(cum_sh[ss][j]), &out[((size_t)(b * NS + ss)) * NF + 536 + lm0 + j]);
        }
    }
}

extern "C" void kernel_launch(void* const* d_in, const int* in_sizes, int n_in,
                              void* d_out, int out_size, void* d_ws, size_t ws_size,
                              hipStream_t stream) {
    const float* x = (const float*)d_in[0];
    float* out = (float*)d_out;
    float* vmstage = (float*)d_ws;   // 32*67*384*4 = 3.3 MB

    k_main<<<NB * (NS / 8), 512, 0, stream>>>(x, out, vmstage);   // 1536 blocks
    k_scan<<<NB * 9, 512, 0, stream>>>(vmstage, out);             // 288 blocks
}

// Round 4
// 128.439 us; speedup vs baseline: 3.6762x; 1.0296x over previous
//
#include <hip/hip_runtime.h>
#include <math.h>

#define NB 32
#define NS 384
#define NLM 543
#define NL 67
#define NF 743

// SEL = FACE(19) + [468..488](21) + [522..542](21) + [11..16](6) = 67
__constant__ int d_SEL[NL] = {
    33, 133, 362, 263, 61, 291, 199, 419, 17, 84, 314, 405, 320, 307, 375, 321, 308, 324, 318,
    468, 469, 470, 471, 472, 473, 474, 475, 476, 477, 478, 479, 480, 481, 482, 483, 484, 485, 486, 487, 488,
    522, 523, 524, 525, 526, 527, 528, 529, 530, 531, 532, 533, 534, 535, 536, 537, 538, 539, 540, 541, 542,
    11, 12, 13, 14, 15, 16
};

__device__ __forceinline__ float fin(float v) { return isfinite(v) ? v : 0.0f; }

// Feature layout per (b,s) row of 743 floats:
// c:[0,134) vel:[134,268) acc:[268,402) vm:[402,469) am:[469,536)
// cum:[536,603) ang:[603,670) dchg:[670,737) dists:[737,743)
// NOTE: NF=743 odd -> row bases alternate 8B alignment; packed float2/float4
// stores are misaligned UB on half the rows. Scalar dword stores (wave-coalesced
// into 256B bursts) are the best legal store pattern here.

__device__ __forceinline__ void gather_norm(const float* __restrict__ xr,
                                            int o0, int o1, bool has1,
                                            float& c0x, float& c0y,
                                            float& c1x, float& c1y) {
    float a0x = xr[o0], a0y = xr[o0 + 1];
    float a1x = 0.f, a1y = 0.f;
    if (has1) { a1x = xr[o1]; a1y = xr[o1 + 1]; }

    float sx = a0x + a1x, sy = a0y + a1y;
    #pragma unroll
    for (int off = 32; off; off >>= 1) { sx += __shfl_xor(sx, off); sy += __shfl_xor(sy, off); }
    const float mx = sx * (1.0f / 67.0f), my = sy * (1.0f / 67.0f);

    c0x = a0x - mx; c0y = a0y - my;
    c1x = a1x - mx; c1y = a1y - my;

    float ss = c0x * c0x + c0y * c0y + (has1 ? (c1x * c1x + c1y * c1y) : 0.f);
    #pragma unroll
    for (int off = 32; off; off >>= 1) ss += __shfl_xor(ss, off);
    const float stdv = sqrtf(ss * (1.0f / 133.0f));
    const float scale = (stdv > 1e-6f) ? (1.0f / stdv) : 1.0f;

    c0x *= scale; c0y *= scale; c1x *= scale; c1y *= scale;
}

// K_main: block = 8 consecutive s of one b (8 waves, 512 threads).
// History: R2's in-kernel decoupled lookback regressed 2.8x (cross-XCD flag
// visibility is ~100s of us — kernel-boundary sync is cheaper than any
// in-kernel cross-block sync on this chip). R3's nontemporal out-stores
// regressed ~4 us (nt forces each scalar store to HBM instead of draining
// lazily from L2) — reverted here.
__global__ __launch_bounds__(512) void k_main(const float* __restrict__ x,
                                              float* __restrict__ out,
                                              float* __restrict__ vmstage) {
    __shared__ float2 csh[10][NL];   // c rows s_base-2 .. s_base+7
    __shared__ float ang_sh[9][NL];  // ang rows s_base-1 .. s_base+7
    __shared__ float vm_sh[8][NL];   // vm rows s_base .. s_base+7

    const int wave = threadIdx.x >> 6;
    const int lane = threadIdx.x & 63;
    const int b = blockIdx.x / 48;              // 48 blocks per batch (384/8)
    const int s_base = (blockIdx.x - b * 48) * 8;
    const int s = s_base + wave;
    const int bs = b * NS + s;

    const int lm0 = lane;
    const bool has1 = (lane < 3);
    const int lm1 = lane + 64;
    const int o0 = d_SEL[lm0] * 3;
    const int o1 = has1 ? d_SEL[lm1] * 3 : 0;

    const float* __restrict__ xb = x + (size_t)(b * NS) * (NLM * 3);

    // own row -> slot wave+2
    float c0x, c0y, c1x, c1y;
    gather_norm(xb + (size_t)s * (NLM * 3), o0, o1, has1, c0x, c0y, c1x, c1y);
    csh[wave + 2][lm0] = make_float2(c0x, c0y);
    if (has1) csh[wave + 2][lm1] = make_float2(c1x, c1y);

    // boundary rows -> slots 1, 0 (zero if out of range)
    if (wave == 0) {
        if (s_base >= 1) {
            float bx, by, b1x, b1y;
            gather_norm(xb + (size_t)(s_base - 1) * (NLM * 3), o0, o1, has1, bx, by, b1x, b1y);
            csh[1][lm0] = make_float2(bx, by);
            if (has1) csh[1][lm1] = make_float2(b1x, b1y);
        } else {
            csh[1][lm0] = make_float2(0.f, 0.f);
            if (has1) csh[1][lm1] = make_float2(0.f, 0.f);
        }
    }
    if (wave == 1) {
        if (s_base >= 2) {
            float bx, by, b1x, b1y;
            gather_norm(xb + (size_t)(s_base - 2) * (NLM * 3), o0, o1, has1, bx, by, b1x, b1y);
            csh[0][lm0] = make_float2(bx, by);
            if (has1) csh[0][lm1] = make_float2(b1x, b1y);
        } else {
            csh[0][lm0] = make_float2(0.f, 0.f);
            if (has1) csh[0][lm1] = make_float2(0.f, 0.f);
        }
    }
    __syncthreads();

    float* __restrict__ row = out + (size_t)bs * NF;

    float ang0_own = 0.f, ang1_own = 0.f;

    #pragma unroll
    for (int half = 0; half < 2; ++half) {
        if (half == 1 && !has1) break;
        const int lm = half ? lm1 : lm0;
        const float cx = half ? c1x : c0x, cy = half ? c1y : c0y;
        const float2 p = csh[wave + 1][lm];     // row s-1
        const float2 q = csh[wave][lm];         // row s-2

        const float vx = (s >= 1) ? (cx - p.x) : 0.f;
        const float vy = (s >= 1) ? (cy - p.y) : 0.f;
        const float v1x = p.x - q.x, v1y = p.y - q.y;   // vel[s-1], valid when s>=2
        const float ax = (s >= 2) ? (vx - v1x) : 0.f;
        const float ay = (s >= 2) ? (vy - v1y) : 0.f;

        const float wx = vx + 1e-8f, wy = vy + 1e-8f;
        const float vm = sqrtf(wx * wx + wy * wy);
        const float ux = ax + 1e-8f, uy = ay + 1e-8f;
        const float am = sqrtf(ux * ux + uy * uy);

        const float ang = atan2f(vy + 1e-8f, vx + 1e-8f);
        if (half) ang1_own = ang; else ang0_own = ang;
        ang_sh[wave + 1][lm] = ang;
        vm_sh[wave][lm] = vm;

        row[2 * lm]       = fin(cx);
        row[2 * lm + 1]   = fin(cy);
        row[134 + 2 * lm] = vx;
        row[135 + 2 * lm] = vy;
        row[268 + 2 * lm] = ax;
        row[269 + 2 * lm] = ay;
        row[402 + lm]     = vm;
        row[469 + lm]     = am;
        row[603 + lm]     = fin(ang);
    }

    // wave 0: angle of boundary row s_base-1 from vel = csh[1]-csh[0].
    // Both slots are zeroed when out of range, and the result is then unused
    // (dchg needs s>=2, and s_base==0 rows 0,1 write zero).
    if (wave == 0) {
        float bvx = csh[1][lm0].x - csh[0][lm0].x;
        float bvy = csh[1][lm0].y - csh[0][lm0].y;
        ang_sh[0][lm0] = atan2f(bvy + 1e-8f, bvx + 1e-8f);
        if (has1) {
            bvx = csh[1][lm1].x - csh[0][lm1].x;
            bvy = csh[1][lm1].y - csh[0][lm1].y;
            ang_sh[0][lm1] = atan2f(bvy + 1e-8f, bvx + 1e-8f);
        }
    }

    // 6 pairwise dists among selected landmarks 0..4 (held in lanes 0..4)
    const int PI_[6] = {0, 0, 1, 1, 2, 2};
    const int PJ_[6] = {1, 2, 2, 3, 3, 4};
    const int p = (lane < 6) ? lane : 0;
    float xi = __shfl(c0x, PI_[p]); float yi = __shfl(c0y, PI_[p]);
    float xj = __shfl(c0x, PJ_[p]); float yj = __shfl(c0y, PJ_[p]);
    if (lane < 6) {
        float dx = xi - xj + 1e-8f, dy = yi - yj + 1e-8f;
        row[737 + lane] = fin(sqrtf(dx * dx + dy * dy));
    }

    __syncthreads();

    // dchg = ang[s] - ang[s-1]; prev-row angle from LDS (same fp value as the
    // inline recompute: identical formula on identical inputs)
    if (s >= 2) {
        row[670 + lm0] = fin(ang0_own - ang_sh[wave][lm0]);
        if (has1) row[670 + lm1] = fin(ang1_own - ang_sh[wave][lm1]);
    } else {
        row[670 + lm0] = 0.f;
        if (has1) row[670 + lm1] = 0.f;
    }

    // Cooperative transposed vmstage write: consecutive threads cover the 8
    // consecutive s of one lm -> 32B contiguous chunks.
    for (int t = threadIdx.x; t < NL * 8; t += 512) {
        const int lm = t >> 3, s8 = t & 7;
        vmstage[((size_t)b * NL + lm) * NS + s_base + s8] = vm_sh[s8][lm];
    }
}

// K_scan: one block per (b, landmark-group) = 32 x 9 = 288 blocks, 512 threads.
// Groups: g<4 -> 8 landmarks, g>=4 -> 7 (4*8+5*7=67). Every wave runs exactly
// <=1 scan chain. Coalesced 256B reads from the transposed stage, identical
// shfl-scan fp order; coalesced burst writes (plain stores — nt regressed).
__global__ __launch_bounds__(512) void k_scan(const float* __restrict__ vmstage,
                                              float* __restrict__ out) {
    __shared__ float cum_sh[NS][9];   // 13.8 KB; stride 9 -> 2-way banks (free)

    const int b = blockIdx.x / 9;
    const int g = blockIdx.x - b * 9;
    const int lm0 = (g < 4) ? g * 8 : 32 + (g - 4) * 7;
    const int cnt = (g < 4) ? 8 : 7;
    const int wave = threadIdx.x >> 6;
    const int lane = threadIdx.x & 63;

    if (wave < cnt) {
        const float* __restrict__ src = vmstage + ((size_t)b * NL + lm0 + wave) * NS;
        float carry = 0.f;
        #pragma unroll
        for (int k = 0; k < 6; ++k) {
            const float v = src[k * 64 + lane];
            float incl = v;
            #pragma unroll
            for (int off = 1; off < 64; off <<= 1) {
                float y = __shfl_up(incl, off);
                if (lane >= off) incl += y;
            }
            cum_sh[k * 64 + lane][wave] = carry + (incl - v);
            carry += __shfl(incl, 63);
        }
    }
    __syncthreads();

    const int total = NS * cnt;
    if (cnt == 8) {
        for (int idx = threadIdx.x; idx < total; idx += 512) {
            const int ss = idx >> 3;
            const int j = idx & 7;
            out[((size_t)(b * NS + ss)) * NF + 536 + lm0 + j] = fin(cum_sh[ss][j]);
        }
    } else {
        for (int idx = threadIdx.x; idx < total; idx += 512) {
            const int ss = idx / 7;             // compiler magic-mul
            const int j = idx - ss * 7;
            out[((size_t)(b * NS + ss)) * NF + 536 + lm0 + j] = fin(cum_sh[ss][j]);
        }
    }
}

extern "C" void kernel_launch(void* const* d_in, const int* in_sizes, int n_in,
                              void* d_out, int out_size, void* d_ws, size_t ws_size,
                              hipStream_t stream) {
    const float* x = (const float*)d_in[0];
    float* out = (float*)d_out;
    float* vmstage = (float*)d_ws;   // 32*67*384*4 = 3.3 MB

    k_main<<<NB * (NS / 8), 512, 0, stream>>>(x, out, vmstage);   // 1536 blocks
    k_scan<<<NB * 9, 512, 0, stream>>>(vmstage, out);             // 288 blocks
}